// Round 7
// baseline (866.051 us; speedup 1.0000x reference)
//
#include <hip/hip_runtime.h>
#include <cstdint>

// ---------- types ----------
using short8 = __attribute__((ext_vector_type(8))) short;
using f32x4  = __attribute__((ext_vector_type(4))) float;
typedef unsigned short ushort_t;

// ---------- bf16 helpers ----------
__device__ __forceinline__ ushort_t f2bf(float f) {
    union { float f; unsigned int u; } v; v.f = f;
    unsigned int r = v.u + 0x7FFFu + ((v.u >> 16) & 1u);   // RNE
    return (ushort_t)(r >> 16);
}
__device__ __forceinline__ float bf2f(ushort_t s) {
    union { unsigned int u; float f; } v; v.u = ((unsigned int)s) << 16;
    return v.f;
}
__device__ __forceinline__ float sigmoidf(float x) { return 1.f / (1.f + expf(-x)); }

__device__ __forceinline__ void async_copy16(void* lds, const void* g) {
    __builtin_amdgcn_global_load_lds((__attribute__((address_space(1))) void*)g,
                                     (__attribute__((address_space(3))) void*)lds,
                                     16, 0, 0);
}

// ---------- constants ----------
// complete 4-ary tree, leaves-first: levels 16384 4096 1024 256 64 16 4 1 (N=21845)
// bf16x3: effective K=1536. A-side stored [hi|lo] (KA=1024), 3rd segment re-reads hi
// via pointer wrap. B-side stored [hi|hi|lo] (KB=1536).
#define KA 1024
#define KB 1536
#define NLEAF 16384
#define NNODE 21845
#define NINT  5461

// tail persistent-kernel geometry: 512 blocks (2/CU) — R5-PROVEN configuration
// (passed full harness incl. post-timing tripwires). R6's 1024-block LDS-staged
// tail failed warm-state-deterministically (suspected barrier/residency race at
// exactly-zero scheduling slack) — shelved pending bisect. This round keeps the
// proven sync structure and only removes the x-half work (xiou MFMA precompute).
#define TAILB 512
#define NXCD  8
#define BPX   (TAILB / NXCD)   // 64 blocks per barrier bucket

// ---------- workspace layout (bytes), total 152,412,160 (~152.4 MB) ----------
#define OFF_WTIOUX  0UL
#define OFF_WTIOUH  (OFF_WTIOUX + 1536UL*KB*2)
#define OFF_WTFX    (OFF_WTIOUH + 1536UL*KB*2)
#define OFF_WTFH    (OFF_WTFX   + 512UL*KB*2)
#define OFF_BIASIOU (OFF_WTFH   + 512UL*KB*2)
#define OFF_BIASF   (OFF_BIASIOU + 1536UL*4)
#define OFF_XHL     (OFF_BIASF  + 512UL*4)
// x_hl: 21848 rows x [hi|lo]. rows 21845..21847 are NEVER written by data kernels
// -> grid-barrier words (zero-initialized every launch by bias_kernel).
#define OFF_HLEAF   (OFF_XHL    + 21848UL*KA*2)
// h_leaf doubles as c_int (fp32) once h_leaf is dead (after L1 hsum+combined).
#define OFF_XF      (OFF_HLEAF  + 16384UL*KA*2)
#define OFF_HSUM    (OFF_XF     + 5464UL*512*4)
#define OFF_CLEAF   (OFF_HSUM   + 4096UL*KA*2)
// c_leaf (33.5MB) is dead after combined(L1); reused as hf32 (fp32 h for rows ioff>=4096).
#define OFF_FC      (OFF_CLEAF  + 16384UL*512*4)
// end = OFF_FC + 4096*512*4 = 152,412,160

// ---------- prep: transpose fp32 W (KxN) -> N x KB bf16, B-side [hi|hi|lo] ----------
__global__ void wsplit_kernel(const float* __restrict__ in, ushort_t* __restrict__ out, int N) {
    __shared__ float t[32][33];
    int kb = blockIdx.x * 32, nb = blockIdx.y * 32;
    for (int i = threadIdx.y; i < 32; i += 8)
        t[i][threadIdx.x] = in[(size_t)(kb + i) * N + nb + threadIdx.x];
    __syncthreads();
    for (int i = threadIdx.y; i < 32; i += 8) {
        float v = t[threadIdx.x][i];
        ushort_t hi = f2bf(v);
        ushort_t lo = f2bf(v - bf2f(hi));
        size_t row = (size_t)(nb + i) * KB + kb + threadIdx.x;
        out[row]        = hi;   // pairs with A hi
        out[row + 512]  = hi;   // pairs with A lo
        out[row + 1024] = lo;   // pairs with A hi (wrapped)
    }
}

__global__ void bias_kernel(const float* __restrict__ b_ioux, const float* __restrict__ b_iouh,
                            const float* __restrict__ b_fx, const float* __restrict__ b_fh,
                            float* __restrict__ bias_iou, float* __restrict__ bias_f,
                            unsigned* __restrict__ bar) {
    int t = blockIdx.x * blockDim.x + threadIdx.x;
    if (t < 1536) bias_iou[t] = b_ioux[t] + b_iouh[t];
    if (t < 512)  bias_f[t]   = b_fx[t] + b_fh[t];
    if (t < 160)  bar[t] = 0u;   // barrier counters (buckets @16-stride, 128 global, 144 release)
}

// ---------- all x rows -> A-side [hi|lo], 4 elems/thread ----------
__global__ void xexp_kernel(const float* __restrict__ x, ushort_t* __restrict__ xe, int n4) {
    int t = blockIdx.x * blockDim.x + threadIdx.x;
    if (t >= n4) return;
    int j = t >> 7, m4 = (t & 127) * 4;
    float4 v = *(const float4*)&x[(size_t)j * 512 + m4];
    ushort4 hi, lo;
    hi.x = f2bf(v.x); lo.x = f2bf(v.x - bf2f(hi.x));
    hi.y = f2bf(v.y); lo.y = f2bf(v.y - bf2f(hi.y));
    hi.z = f2bf(v.z); lo.z = f2bf(v.z - bf2f(hi.z));
    hi.w = f2bf(v.w); lo.w = f2bf(v.w - bf2f(hi.w));
    ushort_t* row = xe + (size_t)j * KA;
    *(ushort4*)&row[m4] = hi;
    *(ushort4*)&row[512 + m4] = lo;
}

// ---------- hsum of 4 children (exact h = hi+lo) -> A-side [hi|lo] ----------
__global__ void hsum_kernel(const ushort_t* __restrict__ h_hl, ushort_t* __restrict__ hsum_hl,
                            int n4) {
    int t = blockIdx.x * blockDim.x + threadIdx.x;
    if (t >= n4) return;
    int j = t >> 7, m4 = (t & 127) * 4;
    const ushort_t* base = h_hl + (size_t)(4 * j) * KA;
    float s0 = 0.f, s1 = 0.f, s2 = 0.f, s3 = 0.f;
#pragma unroll
    for (int r = 0; r < 4; ++r) {
        ushort4 h4 = *(const ushort4*)&base[(size_t)r * KA + m4];
        ushort4 l4 = *(const ushort4*)&base[(size_t)r * KA + 512 + m4];
        s0 += bf2f(h4.x) + bf2f(l4.x);
        s1 += bf2f(h4.y) + bf2f(l4.y);
        s2 += bf2f(h4.z) + bf2f(l4.z);
        s3 += bf2f(h4.w) + bf2f(l4.w);
    }
    ushort4 hi, lo;
    hi.x = f2bf(s0); lo.x = f2bf(s0 - bf2f(hi.x));
    hi.y = f2bf(s1); lo.y = f2bf(s1 - bf2f(hi.y));
    hi.z = f2bf(s2); lo.z = f2bf(s2 - bf2f(hi.z));
    hi.w = f2bf(s3); lo.w = f2bf(s3 - bf2f(hi.w));
    ushort_t* row = hsum_hl + (size_t)j * KA;
    *(ushort4*)&row[m4] = hi;
    *(ushort4*)&row[512 + m4] = lo;
}

// ---------- plain GEMM (bf16x3): x_f precompute + tail x_iou precompute ----------
__global__ __launch_bounds__(256)
void gemm_kernel(int M,
                 const ushort_t* __restrict__ a1,
                 const ushort_t* __restrict__ b1,
                 float* __restrict__ outf, int ldout) {
    __shared__ __align__(16) ushort_t Al[128 * 32];
    __shared__ __align__(16) ushort_t Bl[128 * 32];

    const int tid  = threadIdx.x;
    const int lane = tid & 63, wv = tid >> 6;
    const int l15  = lane & 15, quad = lane >> 4;
    const int wm   = wv >> 1, wn = wv & 1;
    const int m0   = blockIdx.x * 128;
    const int n0   = blockIdx.y * 128;

    const int srow = wv * 16 + (lane >> 2);
    const int kch  = ((lane & 3) ^ ((lane >> 3) & 3)) * 8;
    const int swz  = (quad ^ ((l15 >> 1) & 3)) * 8;

    const ushort_t* a1p[2]; const ushort_t* b1p[2];
#pragma unroll
    for (int r = 0; r < 2; ++r) {
        int rl = m0 + srow + r * 64; if (rl > M - 1) rl = M - 1;
        a1p[r] = a1 + (size_t)rl * KA + kch;
        int nb = n0 + srow + r * 64;
        b1p[r] = b1 + (size_t)nb * KB + kch;
    }

    f32x4 acc[4][4] = {};
    for (int k0 = 0; k0 < KB; k0 += 32) {
        int ka = (k0 < KA) ? k0 : k0 - KA;
        __syncthreads();
#pragma unroll
        for (int r = 0; r < 2; ++r) {
            async_copy16(&Al[(size_t)(wv * 16 + r * 64) * 32], a1p[r] + ka);
            async_copy16(&Bl[(size_t)(wv * 16 + r * 64) * 32], b1p[r] + k0);
        }
        __syncthreads();

        short8 aF[4], bF[4];
#pragma unroll
        for (int i = 0; i < 4; ++i) {
            aF[i] = *(const short8*)&Al[(size_t)(wm * 64 + i * 16 + l15) * 32 + swz];
            bF[i] = *(const short8*)&Bl[(size_t)(wn * 64 + i * 16 + l15) * 32 + swz];
        }
#pragma unroll
        for (int i = 0; i < 4; ++i)
#pragma unroll
            for (int j = 0; j < 4; ++j)
                acc[i][j] = __builtin_amdgcn_mfma_f32_16x16x32_bf16(aF[i], bF[j], acc[i][j], 0, 0, 0);
    }

#pragma unroll
    for (int i = 0; i < 4; ++i) {
        int mbase = m0 + wm * 64 + i * 16 + quad * 4;
#pragma unroll
        for (int j = 0; j < 4; ++j) {
            int n = n0 + wn * 64 + j * 16 + l15;
#pragma unroll
            for (int r = 0; r < 4; ++r) {
                int m = mbase + r;
                if (m < M) outf[(size_t)m * ldout + n] = acc[i][j][r];
            }
        }
    }
}

// ---------- combined per-level dispatch: blockIdx.y<4 -> f-path, else iou-path ----------
__global__ __launch_bounds__(256)
void combined_kernel(int nl,
                     const ushort_t* __restrict__ child_h, const float* __restrict__ c_prev,
                     const float* __restrict__ xf, const float* __restrict__ bias_f,
                     float* __restrict__ fc_out,
                     const ushort_t* __restrict__ x_lvl, const ushort_t* __restrict__ hsum,
                     const ushort_t* __restrict__ Wfh,
                     const ushort_t* __restrict__ Wioux, const ushort_t* __restrict__ Wiouh,
                     float* __restrict__ iou_f, ushort_t* __restrict__ iou_b) {
    __shared__ __align__(16) ushort_t Al[128 * 32];
    __shared__ __align__(16) ushort_t Bl[128 * 32];

    const int by = blockIdx.y;
    const bool fpath = by < 4;
    const int M = fpath ? 4 * nl : nl;
    const int m0 = blockIdx.x * 128;
    if (m0 >= M) return;
    const int n0 = (fpath ? by : by - 4) * 128;

    const ushort_t* A1 = fpath ? child_h : x_lvl;
    const ushort_t* A2 = fpath ? nullptr : hsum;
    const ushort_t* B1 = fpath ? Wfh : Wioux;
    const ushort_t* B2 = fpath ? nullptr : Wiouh;

    const int tid  = threadIdx.x;
    const int lane = tid & 63, wv = tid >> 6;
    const int l15  = lane & 15, quad = lane >> 4;
    const int wm   = wv >> 1, wn = wv & 1;

    const int srow = wv * 16 + (lane >> 2);
    const int kch  = ((lane & 3) ^ ((lane >> 3) & 3)) * 8;
    const int swz  = (quad ^ ((l15 >> 1) & 3)) * 8;

    const ushort_t* a1p[2]; const ushort_t* a2p[2];
    const ushort_t* b1p[2]; const ushort_t* b2p[2];
#pragma unroll
    for (int r = 0; r < 2; ++r) {
        int rl = m0 + srow + r * 64; if (rl > M - 1) rl = M - 1;
        a1p[r] = A1 + (size_t)rl * KA + kch;
        a2p[r] = A2 ? A2 + (size_t)rl * KA + kch : nullptr;
        int nb = n0 + srow + r * 64;
        b1p[r] = B1 + (size_t)nb * KB + kch;
        b2p[r] = B2 ? B2 + (size_t)nb * KB + kch : nullptr;
    }

    f32x4 acc[4][4] = {};
    const int nphase = A2 ? 2 : 1;
    for (int ph = 0; ph < nphase; ++ph) {
        for (int k0 = 0; k0 < KB; k0 += 32) {
            int ka = (k0 < KA) ? k0 : k0 - KA;
            __syncthreads();
#pragma unroll
            for (int r = 0; r < 2; ++r) {
                async_copy16(&Al[(size_t)(wv * 16 + r * 64) * 32], (ph ? a2p[r] : a1p[r]) + ka);
                async_copy16(&Bl[(size_t)(wv * 16 + r * 64) * 32], (ph ? b2p[r] : b1p[r]) + k0);
            }
            __syncthreads();

            short8 aF[4], bF[4];
#pragma unroll
            for (int i = 0; i < 4; ++i) {
                aF[i] = *(const short8*)&Al[(size_t)(wm * 64 + i * 16 + l15) * 32 + swz];
                bF[i] = *(const short8*)&Bl[(size_t)(wn * 64 + i * 16 + l15) * 32 + swz];
            }
#pragma unroll
            for (int i = 0; i < 4; ++i)
#pragma unroll
                for (int j = 0; j < 4; ++j)
                    acc[i][j] = __builtin_amdgcn_mfma_f32_16x16x32_bf16(aF[i], bF[j], acc[i][j], 0, 0, 0);
        }
    }

    if (fpath) {
#pragma unroll
        for (int i = 0; i < 4; ++i) {
            int mbase = m0 + wm * 64 + i * 16 + quad * 4;   // = 4*jg
            if (mbase < M) {
                int jg = mbase >> 2;
#pragma unroll
                for (int j = 0; j < 4; ++j) {
                    int n = n0 + wn * 64 + j * 16 + l15;
                    float add = xf[(size_t)jg * 512 + n] + bias_f[n];
                    float fc = 0.f;
#pragma unroll
                    for (int r = 0; r < 4; ++r) {
                        float f = sigmoidf(acc[i][j][r] + add);
                        fc += f * c_prev[(size_t)(mbase + r) * 512 + n];
                    }
                    fc_out[(size_t)jg * 512 + n] = fc;
                }
            }
        }
    } else {
#pragma unroll
        for (int i = 0; i < 4; ++i) {
            int mbase = m0 + wm * 64 + i * 16 + quad * 4;
#pragma unroll
            for (int j = 0; j < 4; ++j) {
                int n = n0 + wn * 64 + j * 16 + l15;
#pragma unroll
                for (int r = 0; r < 4; ++r) {
                    int m = mbase + r;
                    if (m < M) {
                        if (iou_b) iou_b[(size_t)m * 1536 + n] = f2bf(acc[i][j][r]);
                        else       iou_f[(size_t)m * 1536 + n] = acc[i][j][r];
                    }
                }
            }
        }
    }
}

// ---------- fused leaf: iou-GEMM + LSTM cell in-register ----------
__global__ __launch_bounds__(256)
void fused_leaf_kernel(int M,
                       const ushort_t* __restrict__ a1,
                       const ushort_t* __restrict__ b1,
                       const float* __restrict__ bias_iou,
                       float* __restrict__ c_out,
                       ushort_t* __restrict__ h_out) {
    __shared__ __align__(16) ushort_t Al[128 * 32];       // 8 KB
    __shared__ __align__(16) ushort_t Bl[3 * 64 * 32];    // 12 KB

    const int tid  = threadIdx.x;
    const int lane = tid & 63, wv = tid >> 6;
    const int l15  = lane & 15, quad = lane >> 4;
    const int m0   = blockIdx.x * 128;
    const int n0   = blockIdx.y * 64;

    const int srow = wv * 16 + (lane >> 2);
    const int kch  = ((lane & 3) ^ ((lane >> 3) & 3)) * 8;
    const int swz  = (quad ^ ((l15 >> 1) & 3)) * 8;

    const ushort_t* a1p[2]; const ushort_t* b1p[3];
#pragma unroll
    for (int r = 0; r < 2; ++r) {
        int rl = m0 + srow + r * 64; if (rl > M - 1) rl = M - 1;
        a1p[r] = a1 + (size_t)rl * KA + kch;
    }
#pragma unroll
    for (int g = 0; g < 3; ++g)
        b1p[g] = b1 + (size_t)(g * 512 + n0 + srow) * KB + kch;

    f32x4 acc[3][2][4] = {};
    for (int k0 = 0; k0 < KB; k0 += 32) {
        int ka = (k0 < KA) ? k0 : k0 - KA;
        __syncthreads();
#pragma unroll
        for (int r = 0; r < 2; ++r)
            async_copy16(&Al[(size_t)(wv * 16 + r * 64) * 32], a1p[r] + ka);
#pragma unroll
        for (int g = 0; g < 3; ++g)
            async_copy16(&Bl[(size_t)(g * 64 + wv * 16) * 32], b1p[g] + k0);
        __syncthreads();

        short8 aF[2];
#pragma unroll
        for (int i = 0; i < 2; ++i)
            aF[i] = *(const short8*)&Al[(size_t)(wv * 32 + i * 16 + l15) * 32 + swz];
#pragma unroll
        for (int g = 0; g < 3; ++g) {
            short8 bF[4];
#pragma unroll
            for (int j = 0; j < 4; ++j)
                bF[j] = *(const short8*)&Bl[(size_t)(g * 64 + j * 16 + l15) * 32 + swz];
#pragma unroll
            for (int i = 0; i < 2; ++i)
#pragma unroll
                for (int j = 0; j < 4; ++j)
                    acc[g][i][j] = __builtin_amdgcn_mfma_f32_16x16x32_bf16(aF[i], bF[j], acc[g][i][j], 0, 0, 0);
        }
    }

#pragma unroll
    for (int i = 0; i < 2; ++i) {
        int mbase = m0 + wv * 32 + i * 16 + quad * 4;
#pragma unroll
        for (int r = 0; r < 4; ++r) {
            int m = mbase + r;
            if (m < M) {
#pragma unroll
                for (int j = 0; j < 4; ++j) {
                    int n = n0 + j * 16 + l15;
                    float iv = sigmoidf(acc[0][i][j][r] + bias_iou[n]);
                    float ov = sigmoidf(acc[1][i][j][r] + bias_iou[512 + n]);
                    float uv = tanhf(  acc[2][i][j][r] + bias_iou[1024 + n]);
                    float c = iv * uv;
                    float h = ov * tanhf(c);
                    c_out[(size_t)m * 512 + n] = c;
                    ushort_t hi = f2bf(h), lo = f2bf(h - bf2f(hi));
                    h_out[(size_t)m * KA + n] = hi;
                    h_out[(size_t)m * KA + 512 + n] = lo;
                }
            }
        }
    }
}

// ---------- elementwise cell (L1/L2), 4 elems/thread; optional fp32-h side output ----------
template <bool IOU_BF>
__global__ void cell_kernel(const void* __restrict__ iou_v, const float* __restrict__ bias_iou,
                            const float* __restrict__ fc,
                            ushort_t* __restrict__ h_out, float* __restrict__ c_out,
                            int n4, float* __restrict__ outp, float* __restrict__ hf_out) {
    int t = blockIdx.x * blockDim.x + threadIdx.x;
    if (t >= n4) return;
    int j = t >> 7, m4 = (t & 127) * 4;
    float pi[4], po[4], pu[4];
    if constexpr (IOU_BF) {
        const ushort_t* row = (const ushort_t*)iou_v + (size_t)j * 1536;
        ushort4 a = *(const ushort4*)&row[m4];
        ushort4 b = *(const ushort4*)&row[512 + m4];
        ushort4 c = *(const ushort4*)&row[1024 + m4];
        pi[0]=bf2f(a.x); pi[1]=bf2f(a.y); pi[2]=bf2f(a.z); pi[3]=bf2f(a.w);
        po[0]=bf2f(b.x); po[1]=bf2f(b.y); po[2]=bf2f(b.z); po[3]=bf2f(b.w);
        pu[0]=bf2f(c.x); pu[1]=bf2f(c.y); pu[2]=bf2f(c.z); pu[3]=bf2f(c.w);
    } else {
        const float* row = (const float*)iou_v + (size_t)j * 1536;
        float4 a = *(const float4*)&row[m4];
        float4 b = *(const float4*)&row[512 + m4];
        float4 c = *(const float4*)&row[1024 + m4];
        pi[0]=a.x; pi[1]=a.y; pi[2]=a.z; pi[3]=a.w;
        po[0]=b.x; po[1]=b.y; po[2]=b.z; po[3]=b.w;
        pu[0]=c.x; pu[1]=c.y; pu[2]=c.z; pu[3]=c.w;
    }
    float4 bi = *(const float4*)&bias_iou[m4];
    float4 bo = *(const float4*)&bias_iou[512 + m4];
    float4 bu = *(const float4*)&bias_iou[1024 + m4];
    float4 fcv = *(const float4*)&fc[(size_t)j * 512 + m4];
    float bia[4] = {bi.x, bi.y, bi.z, bi.w};
    float boa[4] = {bo.x, bo.y, bo.z, bo.w};
    float bua[4] = {bu.x, bu.y, bu.z, bu.w};
    float fca[4] = {fcv.x, fcv.y, fcv.z, fcv.w};
    float cv[4], hv[4];
#pragma unroll
    for (int q = 0; q < 4; ++q) {
        float iv = sigmoidf(pi[q] + bia[q]);
        float ov = sigmoidf(po[q] + boa[q]);
        float uv = tanhf(  pu[q] + bua[q]);
        cv[q] = iv * uv + fca[q];
        hv[q] = ov * tanhf(cv[q]);
    }
    *(float4*)&c_out[(size_t)j * 512 + m4] = float4{cv[0], cv[1], cv[2], cv[3]};
    ushort4 hi, lo;
    hi.x = f2bf(hv[0]); lo.x = f2bf(hv[0] - bf2f(hi.x));
    hi.y = f2bf(hv[1]); lo.y = f2bf(hv[1] - bf2f(hi.y));
    hi.z = f2bf(hv[2]); lo.z = f2bf(hv[2] - bf2f(hi.z));
    hi.w = f2bf(hv[3]); lo.w = f2bf(hv[3] - bf2f(hi.w));
    ushort_t* hr = h_out + (size_t)j * KA;
    *(ushort4*)&hr[m4] = hi;
    *(ushort4*)&hr[512 + m4] = lo;
    if (hf_out) *(float4*)&hf_out[(size_t)j * 512 + m4] = float4{hv[0], hv[1], hv[2], hv[3]};
    if (outp) *(float4*)&outp[m4] = float4{hv[0], hv[1], hv[2], hv[3]};
}

// ================= persistent tail (levels 3..7, nl=256..1) =================
// R5-PROVEN structure: 512 blocks, 9 grid barriers (gemm/cell split per level),
// hierarchical bucket barrier, relaxed poll + single acquire fence. This round:
// x-half removed from tail_gemm (precomputed by MFMA into xiou).

__device__ __forceinline__ void grid_barrier(unsigned* bar, unsigned base, unsigned step) {
    __syncthreads();
    if (threadIdx.x == 0) {
        __threadfence();   // release: make this block's stage writes visible
        const int bkt = (int)(blockIdx.x & (NXCD - 1));
        unsigned old = __hip_atomic_fetch_add(&bar[16 * bkt], 1u, __ATOMIC_ACQ_REL, __HIP_MEMORY_SCOPE_AGENT);
        if (((old + 1u) & (unsigned)(BPX - 1)) == 0u) {       // bucket complete for this step
            unsigned g = __hip_atomic_fetch_add(&bar[128], 1u, __ATOMIC_ACQ_REL, __HIP_MEMORY_SCOPE_AGENT);
            if (((g + 1u) & (unsigned)(NXCD - 1)) == 0u)      // all buckets complete
                __hip_atomic_fetch_add(&bar[144], 1u, __ATOMIC_ACQ_REL, __HIP_MEMORY_SCOPE_AGENT);
        }
        while ((unsigned)(__hip_atomic_load(&bar[144], __ATOMIC_RELAXED, __HIP_MEMORY_SCOPE_AGENT) - base) < step)
            __builtin_amdgcn_s_sleep(2);
        __threadfence();   // acquire ONCE: invalidate stale cache before reading stage data
    }
    __syncthreads();
}

// G-stage: unit (jg, s, n) per thread. n = 64*(blockIdx&7) + lane (XCD-local
// weight columns); sub = (blockIdx>>3)*4 + wave selects (jg, s).
// iou-h = (sum of 4 child h)@Wh; f[r] = h_child_r@Wf. Split-K fp32 partials.
// (x-half precomputed into xiou — consumed by tail_cell.)
template <int S, int NL>
__device__ void tail_gemm(int ioff, int ioffp,
                          const float* __restrict__ hf,
                          const float* __restrict__ Wh, const float* __restrict__ Wf,
                          float* __restrict__ iou_part, float* __restrict__ f_part) {
    constexpr int JG = (NL + 3) >> 2;
    int sub = (int)(blockIdx.x >> 3) * 4 + (int)(threadIdx.x >> 6);
    if (sub >= JG * S) return;
    const int n = ((int)(blockIdx.x & 7) << 6) | ((int)threadIdx.x & 63);
    const int jg = __builtin_amdgcn_readfirstlane(sub / S);
    const int s  = __builtin_amdgcn_readfirstlane(sub % S);
    const int jbase = jg << 2;

    const float* hb[4];
#pragma unroll
    for (int p = 0; p < 4; ++p) {
        int jc = jbase + p; if (jc > NL - 1) jc = NL - 1;   // clamp (only root level)
        hb[p] = hf + (size_t)(ioffp - 4096 + 4 * jc) * 512;
    }
    float aI[4][3] = {}; float aF[4][4] = {};
    // h-half: iou += hsum * Wiouh ; f[r] += h_r * Wfh
#pragma unroll 4
    for (int k = s; k < 512; k += S) {
        const size_t kr = (size_t)k * 1536;
        float w0 = Wh[kr + n], w1 = Wh[kr + 512 + n], w2 = Wh[kr + 1024 + n];
        float wf = Wf[(size_t)k * 512 + n];
#pragma unroll
        for (int p = 0; p < 4; ++p) {
            float h0 = hb[p][k], h1 = hb[p][512 + k], h2 = hb[p][1024 + k], h3 = hb[p][1536 + k];
            float hs = (h0 + h1) + (h2 + h3);
            aI[p][0] += hs * w0; aI[p][1] += hs * w1; aI[p][2] += hs * w2;
            aF[p][0] += h0 * wf; aF[p][1] += h1 * wf; aF[p][2] += h2 * wf; aF[p][3] += h3 * wf;
        }
    }
#pragma unroll
    for (int p = 0; p < 4; ++p) {
        int j = jbase + p;
        if (j < NL) {
#pragma unroll
            for (int g = 0; g < 3; ++g)
                iou_part[(((size_t)s * NL + j) * 3 + g) * 512 + n] = aI[p][g];
#pragma unroll
            for (int r = 0; r < 4; ++r)
                f_part[((size_t)s * 4 * NL + 4 * j + r) * 512 + n] = aF[p][r];
        }
    }
}

// C-stage: unit (j, n) per thread; sums S partials, adds precomputed xiou
// (x@Wioux) + biases, applies gates, writes c/h (fp32). NL==1 -> root output.
template <int S, int NL>
__device__ void tail_cell(int ioff, int ioffp,
                          const float* __restrict__ xiou,
                          float* __restrict__ hf, float* __restrict__ c_int,
                          const float* __restrict__ xf,
                          const float* __restrict__ bias_iou, const float* __restrict__ bias_f,
                          const float* __restrict__ iou_part, const float* __restrict__ f_part,
                          float* __restrict__ out) {
    int sub = (int)(blockIdx.x >> 3) * 4 + (int)(threadIdx.x >> 6);
    if (sub >= NL) return;
    const int n = ((int)(blockIdx.x & 7) << 6) | ((int)threadIdx.x & 63);
    const int j = __builtin_amdgcn_readfirstlane(sub);
    const size_t xr = (size_t)(ioff - 5120 + j) * 1536;
    float g0 = xiou[xr + n]        + bias_iou[n];
    float g1 = xiou[xr + 512 + n]  + bias_iou[512 + n];
    float g2 = xiou[xr + 1024 + n] + bias_iou[1024 + n];
    float f0 = 0.f, f1 = 0.f, f2 = 0.f, f3 = 0.f;
#pragma unroll 4
    for (int s = 0; s < S; ++s) {
        const float* ip = iou_part + (((size_t)s * NL + j) * 3) * 512 + n;
        g0 += ip[0]; g1 += ip[512]; g2 += ip[1024];
        const float* fp = f_part + ((size_t)s * 4 * NL + 4 * j) * 512 + n;
        f0 += fp[0]; f1 += fp[512]; f2 += fp[1024]; f3 += fp[1536];
    }
    float iv = sigmoidf(g0), ov = sigmoidf(g1), uv = tanhf(g2);
    float add = xf[(size_t)(ioff + j) * 512 + n] + bias_f[n];
    float fc = sigmoidf(f0 + add) * c_int[(size_t)(ioffp + 4 * j + 0) * 512 + n]
             + sigmoidf(f1 + add) * c_int[(size_t)(ioffp + 4 * j + 1) * 512 + n]
             + sigmoidf(f2 + add) * c_int[(size_t)(ioffp + 4 * j + 2) * 512 + n]
             + sigmoidf(f3 + add) * c_int[(size_t)(ioffp + 4 * j + 3) * 512 + n];
    float c = iv * uv + fc;
    float h = ov * tanhf(c);
    c_int[(size_t)(ioff + j) * 512 + n] = c;
    hf[(size_t)(ioff - 4096 + j) * 512 + n] = h;
    if (NL == 1) out[n] = h;   // root
}

__global__ __launch_bounds__(256, 4)
void tail_kernel(const float* __restrict__ xiou, float* __restrict__ hf,
                 float* __restrict__ c_int, const float* __restrict__ xf,
                 const float* __restrict__ Wh, const float* __restrict__ Wf,
                 const float* __restrict__ bias_iou, const float* __restrict__ bias_f,
                 float* __restrict__ iou_part, float* __restrict__ f_part,
                 unsigned* __restrict__ bar, float* __restrict__ out) {
    __shared__ unsigned s_base;
    if (threadIdx.x == 0)
        s_base = __hip_atomic_load(&bar[144], __ATOMIC_RELAXED, __HIP_MEMORY_SCOPE_AGENT);
    __syncthreads();
    const unsigned base = s_base;
    unsigned step = 0;

    // L3: nl=256
    tail_gemm<4, 256>(5120, 4096, hf, Wh, Wf, iou_part, f_part);
    grid_barrier(bar, base, ++step);
    tail_cell<4, 256>(5120, 4096, xiou, hf, c_int, xf, bias_iou, bias_f, iou_part, f_part, out);
    grid_barrier(bar, base, ++step);
    // L4: nl=64
    tail_gemm<16, 64>(5376, 5120, hf, Wh, Wf, iou_part, f_part);
    grid_barrier(bar, base, ++step);
    tail_cell<16, 64>(5376, 5120, xiou, hf, c_int, xf, bias_iou, bias_f, iou_part, f_part, out);
    grid_barrier(bar, base, ++step);
    // L5: nl=16
    tail_gemm<64, 16>(5440, 5376, hf, Wh, Wf, iou_part, f_part);
    grid_barrier(bar, base, ++step);
    tail_cell<64, 16>(5440, 5376, xiou, hf, c_int, xf, bias_iou, bias_f, iou_part, f_part, out);
    grid_barrier(bar, base, ++step);
    // L6: nl=4
    tail_gemm<64, 4>(5456, 5440, hf, Wh, Wf, iou_part, f_part);
    grid_barrier(bar, base, ++step);
    tail_cell<64, 4>(5456, 5440, xiou, hf, c_int, xf, bias_iou, bias_f, iou_part, f_part, out);
    grid_barrier(bar, base, ++step);
    // L7 (root): nl=1
    tail_gemm<64, 1>(5460, 5456, hf, Wh, Wf, iou_part, f_part);
    grid_barrier(bar, base, ++step);
    tail_cell<64, 1>(5460, 5456, xiou, hf, c_int, xf, bias_iou, bias_f, iou_part, f_part, out);
}

// ---------- host ----------
extern "C" void kernel_launch(void* const* d_in, const int* in_sizes, int n_in,
                              void* d_out, int out_size, void* d_ws, size_t ws_size,
                              hipStream_t stream) {
    const float* x       = (const float*)d_in[0];
    // d_in[1] = children: fixed complete 4-ary tree, contiguous levels — not needed
    const float* W_ioux  = (const float*)d_in[2];
    const float* b_ioux  = (const float*)d_in[3];
    const float* W_iouh  = (const float*)d_in[4];
    const float* b_iouh  = (const float*)d_in[5];
    const float* W_fx    = (const float*)d_in[6];
    const float* b_fx    = (const float*)d_in[7];
    const float* W_fh    = (const float*)d_in[8];
    const float* b_fh    = (const float*)d_in[9];
    float* out = (float*)d_out;
    char* ws = (char*)d_ws;

    ushort_t* WTioux = (ushort_t*)(ws + OFF_WTIOUX);
    ushort_t* WTiouh = (ushort_t*)(ws + OFF_WTIOUH);
    ushort_t* WTfx   = (ushort_t*)(ws + OFF_WTFX);
    ushort_t* WTfh   = (ushort_t*)(ws + OFF_WTFH);
    float*    bias_iou = (float*)(ws + OFF_BIASIOU);
    float*    bias_f   = (float*)(ws + OFF_BIASF);
    ushort_t* x_hl   = (ushort_t*)(ws + OFF_XHL);
    ushort_t* h_int  = x_hl;                               // rows 0..5460 (dead leaf x)
    ushort_t* iou_b  = x_hl + (size_t)5464 * KA;           // rows 5464.. (dead leaf x)
    float*    iou_f  = (float*)iou_b;
    ushort_t* h_leaf = (ushort_t*)(ws + OFF_HLEAF);
    float*    c_int  = (float*)(ws + OFF_HLEAF);           // alias; live after h_leaf dead
    float*    xf32   = (float*)(ws + OFF_XF);
    ushort_t* hsum_hl= (ushort_t*)(ws + OFF_HSUM);
    float*    c_leaf = (float*)(ws + OFF_CLEAF);
    float*    fc_buf = (float*)(ws + OFF_FC);
    // tail-only views over dead regions:
    float*    hf32     = (float*)(ws + OFF_CLEAF);         // fp32 h rows (ioff-4096); c_leaf dead after combined(L1)
    float*    xiou     = fc_buf;                           // 341x1536 fp32 (2.1MB); fc dead after cell(L2)
    float*    iou_part = iou_f;                            // 6.3MB, iou scratch dead after cell(L2)
    float*    f_part   = iou_f + 1572864;                  // 8.4MB, inside dead region (14.7 < 22.4MB)
    unsigned* barp     = (unsigned*)(x_hl + (size_t)21845 * KA);  // never-written pad rows

    wsplit_kernel<<<dim3(16, 48), dim3(32, 8), 0, stream>>>(W_ioux, WTioux, 1536);
    wsplit_kernel<<<dim3(16, 48), dim3(32, 8), 0, stream>>>(W_iouh, WTiouh, 1536);
    wsplit_kernel<<<dim3(16, 16), dim3(32, 8), 0, stream>>>(W_fx,   WTfx,   512);
    wsplit_kernel<<<dim3(16, 16), dim3(32, 8), 0, stream>>>(W_fh,   WTfh,   512);
    bias_kernel<<<6, 256, 0, stream>>>(b_ioux, b_iouh, b_fx, b_fh, bias_iou, bias_f, barp);

    // all-node x expansion
    xexp_kernel<<<(NNODE * 128 + 255) / 256, 256, 0, stream>>>(x, x_hl, NNODE * 128);

    // x_f for internal nodes (once): M=5461, N=512
    gemm_kernel<<<dim3(43, 4), 256, 0, stream>>>(
        NINT, x_hl + (size_t)NLEAF * KA, WTfx, xf32, 512);

    // ---- leaf level: fused iou-GEMM + cell ----
    fused_leaf_kernel<<<dim3(128, 8), 256, 0, stream>>>(
        NLEAF, x_hl, WTioux, bias_iou, c_leaf, h_leaf);

    // ---- level 1 (nl=4096): hsum -> combined(f || iou bf16) -> cell ----
    {
        const int nl = 4096, n4 = nl * 128, M4 = 4 * nl;
        hsum_kernel<<<(n4 + 255) / 256, 256, 0, stream>>>(h_leaf, hsum_hl, n4);
        combined_kernel<<<dim3((M4 + 127) / 128, 16), 256, 0, stream>>>(
            nl, h_leaf, c_leaf, xf32, bias_f, fc_buf,
            x_hl + (size_t)16384 * KA, hsum_hl, WTfh, WTioux, WTiouh,
            nullptr, iou_b);
        cell_kernel<true><<<(n4 + 255) / 256, 256, 0, stream>>>(
            iou_b, bias_iou, fc_buf, h_int, c_int, n4, nullptr, nullptr);
    }
    // ---- level 2 (nl=1024): hsum -> combined(f || iou fp32) -> cell (+fp32 h for tail) ----
    {
        const int nl = 1024, n4 = nl * 128, M4 = 4 * nl, ioff = 4096;
        hsum_kernel<<<(n4 + 255) / 256, 256, 0, stream>>>(h_int, hsum_hl, n4);
        combined_kernel<<<dim3((M4 + 127) / 128, 16), 256, 0, stream>>>(
            nl, h_int, c_int, xf32 + (size_t)ioff * 512, bias_f, fc_buf,
            x_hl + (size_t)20480 * KA, hsum_hl, WTfh, WTioux, WTiouh,
            iou_f, nullptr);
        cell_kernel<false><<<(n4 + 255) / 256, 256, 0, stream>>>(
            iou_f, bias_iou, fc_buf, h_int + (size_t)ioff * KA, c_int + (size_t)ioff * 512,
            n4, nullptr, hf32);
    }
    // ---- x_iou for tail nodes 5120..5460 (M=341, N=1536) -> xiou (fc region) ----
    gemm_kernel<<<dim3(3, 12), 256, 0, stream>>>(
        341, x_hl + (size_t)(NLEAF + 5120) * KA, WTioux, xiou, 1536);

    // ---- levels 3..7 (nl=256..1): one persistent fp32-VALU kernel, 9 grid barriers ----
    tail_kernel<<<TAILB, 256, 0, stream>>>(
        xiou, hf32, c_int, xf32, W_iouh, W_fh, bias_iou, bias_f,
        iou_part, f_part, barp, out);

    (void)d_in; (void)in_sizes; (void)n_in; (void)out_size; (void)ws_size;
}

// Round 8
// 831.282 us; speedup vs baseline: 1.0418x; 1.0418x over previous
//
#include <hip/hip_runtime.h>
#include <cstdint>

// ---------- types ----------
using short8 = __attribute__((ext_vector_type(8))) short;
using f32x4  = __attribute__((ext_vector_type(4))) float;
typedef unsigned short ushort_t;

// ---------- bf16 helpers ----------
__device__ __forceinline__ ushort_t f2bf(float f) {
    union { float f; unsigned int u; } v; v.f = f;
    unsigned int r = v.u + 0x7FFFu + ((v.u >> 16) & 1u);   // RNE
    return (ushort_t)(r >> 16);
}
__device__ __forceinline__ float bf2f(ushort_t s) {
    union { unsigned int u; float f; } v; v.u = ((unsigned int)s) << 16;
    return v.f;
}
__device__ __forceinline__ float sigmoidf(float x) { return 1.f / (1.f + expf(-x)); }

__device__ __forceinline__ void async_copy16(void* lds, const void* g) {
    __builtin_amdgcn_global_load_lds((__attribute__((address_space(1))) void*)g,
                                     (__attribute__((address_space(3))) void*)lds,
                                     16, 0, 0);
}

// ---------- constants ----------
// complete 4-ary tree, leaves-first: levels 16384 4096 1024 256 64 16 4 1 (N=21845)
// bf16x3: effective K=1536. A-side stored [hi|lo] (KA=1024), 3rd segment re-reads hi
// via pointer wrap. B-side stored [hi|hi|lo] (KB=1536).
#define KA 1024
#define KB 1536
#define NLEAF 16384
#define NNODE 21845
#define NINT  5461

// tail persistent-kernel geometry: 512 blocks (2/CU) — R5/R7-PROVEN sync config.
// R7 lesson: all tail variants converge ~400us because the gemm inner loop's 16
// wave-uniform SCALAR h-loads per k serialize at L2 latency (VALUBusy 6.9%).
// This round: stage the block's 16 child-h rows in LDS (the 4 waves provably
// share one jg at every level), read h as conflict-free LDS broadcasts.
// Inter-block structure (grid/barriers/partials/cell) unchanged from R7.
#define TAILB 512
#define NXCD  8
#define BPX   (TAILB / NXCD)   // 64 blocks per barrier bucket

// ---------- workspace layout (bytes), total 152,412,160 (~152.4 MB) ----------
#define OFF_WTIOUX  0UL
#define OFF_WTIOUH  (OFF_WTIOUX + 1536UL*KB*2)
#define OFF_WTFX    (OFF_WTIOUH + 1536UL*KB*2)
#define OFF_WTFH    (OFF_WTFX   + 512UL*KB*2)
#define OFF_BIASIOU (OFF_WTFH   + 512UL*KB*2)
#define OFF_BIASF   (OFF_BIASIOU + 1536UL*4)
#define OFF_XHL     (OFF_BIASF  + 512UL*4)
// x_hl: 21848 rows x [hi|lo]. rows 21845..21847 are NEVER written by data kernels
// -> grid-barrier words (zero-initialized every launch by bias_kernel).
#define OFF_HLEAF   (OFF_XHL    + 21848UL*KA*2)
// h_leaf doubles as c_int (fp32) once h_leaf is dead (after L1 hsum+combined).
#define OFF_XF      (OFF_HLEAF  + 16384UL*KA*2)
#define OFF_HSUM    (OFF_XF     + 5464UL*512*4)
#define OFF_CLEAF   (OFF_HSUM   + 4096UL*KA*2)
// c_leaf (33.5MB) is dead after combined(L1); reused as hf32 (fp32 h for rows ioff>=4096).
#define OFF_FC      (OFF_CLEAF  + 16384UL*512*4)
// end = OFF_FC + 4096*512*4 = 152,412,160

// ---------- prep: transpose fp32 W (KxN) -> N x KB bf16, B-side [hi|hi|lo] ----------
__global__ void wsplit_kernel(const float* __restrict__ in, ushort_t* __restrict__ out, int N) {
    __shared__ float t[32][33];
    int kb = blockIdx.x * 32, nb = blockIdx.y * 32;
    for (int i = threadIdx.y; i < 32; i += 8)
        t[i][threadIdx.x] = in[(size_t)(kb + i) * N + nb + threadIdx.x];
    __syncthreads();
    for (int i = threadIdx.y; i < 32; i += 8) {
        float v = t[threadIdx.x][i];
        ushort_t hi = f2bf(v);
        ushort_t lo = f2bf(v - bf2f(hi));
        size_t row = (size_t)(nb + i) * KB + kb + threadIdx.x;
        out[row]        = hi;   // pairs with A hi
        out[row + 512]  = hi;   // pairs with A lo
        out[row + 1024] = lo;   // pairs with A hi (wrapped)
    }
}

__global__ void bias_kernel(const float* __restrict__ b_ioux, const float* __restrict__ b_iouh,
                            const float* __restrict__ b_fx, const float* __restrict__ b_fh,
                            float* __restrict__ bias_iou, float* __restrict__ bias_f,
                            unsigned* __restrict__ bar) {
    int t = blockIdx.x * blockDim.x + threadIdx.x;
    if (t < 1536) bias_iou[t] = b_ioux[t] + b_iouh[t];
    if (t < 512)  bias_f[t]   = b_fx[t] + b_fh[t];
    if (t < 160)  bar[t] = 0u;   // barrier counters (buckets @16-stride, 128 global, 144 release)
}

// ---------- all x rows -> A-side [hi|lo], 4 elems/thread ----------
__global__ void xexp_kernel(const float* __restrict__ x, ushort_t* __restrict__ xe, int n4) {
    int t = blockIdx.x * blockDim.x + threadIdx.x;
    if (t >= n4) return;
    int j = t >> 7, m4 = (t & 127) * 4;
    float4 v = *(const float4*)&x[(size_t)j * 512 + m4];
    ushort4 hi, lo;
    hi.x = f2bf(v.x); lo.x = f2bf(v.x - bf2f(hi.x));
    hi.y = f2bf(v.y); lo.y = f2bf(v.y - bf2f(hi.y));
    hi.z = f2bf(v.z); lo.z = f2bf(v.z - bf2f(hi.z));
    hi.w = f2bf(v.w); lo.w = f2bf(v.w - bf2f(hi.w));
    ushort_t* row = xe + (size_t)j * KA;
    *(ushort4*)&row[m4] = hi;
    *(ushort4*)&row[512 + m4] = lo;
}

// ---------- hsum of 4 children (exact h = hi+lo) -> A-side [hi|lo] ----------
__global__ void hsum_kernel(const ushort_t* __restrict__ h_hl, ushort_t* __restrict__ hsum_hl,
                            int n4) {
    int t = blockIdx.x * blockDim.x + threadIdx.x;
    if (t >= n4) return;
    int j = t >> 7, m4 = (t & 127) * 4;
    const ushort_t* base = h_hl + (size_t)(4 * j) * KA;
    float s0 = 0.f, s1 = 0.f, s2 = 0.f, s3 = 0.f;
#pragma unroll
    for (int r = 0; r < 4; ++r) {
        ushort4 h4 = *(const ushort4*)&base[(size_t)r * KA + m4];
        ushort4 l4 = *(const ushort4*)&base[(size_t)r * KA + 512 + m4];
        s0 += bf2f(h4.x) + bf2f(l4.x);
        s1 += bf2f(h4.y) + bf2f(l4.y);
        s2 += bf2f(h4.z) + bf2f(l4.z);
        s3 += bf2f(h4.w) + bf2f(l4.w);
    }
    ushort4 hi, lo;
    hi.x = f2bf(s0); lo.x = f2bf(s0 - bf2f(hi.x));
    hi.y = f2bf(s1); lo.y = f2bf(s1 - bf2f(hi.y));
    hi.z = f2bf(s2); lo.z = f2bf(s2 - bf2f(hi.z));
    hi.w = f2bf(s3); lo.w = f2bf(s3 - bf2f(hi.w));
    ushort_t* row = hsum_hl + (size_t)j * KA;
    *(ushort4*)&row[m4] = hi;
    *(ushort4*)&row[512 + m4] = lo;
}

// ---------- plain GEMM (bf16x3): x_f precompute + tail x_iou precompute ----------
__global__ __launch_bounds__(256)
void gemm_kernel(int M,
                 const ushort_t* __restrict__ a1,
                 const ushort_t* __restrict__ b1,
                 float* __restrict__ outf, int ldout) {
    __shared__ __align__(16) ushort_t Al[128 * 32];
    __shared__ __align__(16) ushort_t Bl[128 * 32];

    const int tid  = threadIdx.x;
    const int lane = tid & 63, wv = tid >> 6;
    const int l15  = lane & 15, quad = lane >> 4;
    const int wm   = wv >> 1, wn = wv & 1;
    const int m0   = blockIdx.x * 128;
    const int n0   = blockIdx.y * 128;

    const int srow = wv * 16 + (lane >> 2);
    const int kch  = ((lane & 3) ^ ((lane >> 3) & 3)) * 8;
    const int swz  = (quad ^ ((l15 >> 1) & 3)) * 8;

    const ushort_t* a1p[2]; const ushort_t* b1p[2];
#pragma unroll
    for (int r = 0; r < 2; ++r) {
        int rl = m0 + srow + r * 64; if (rl > M - 1) rl = M - 1;
        a1p[r] = a1 + (size_t)rl * KA + kch;
        int nb = n0 + srow + r * 64;
        b1p[r] = b1 + (size_t)nb * KB + kch;
    }

    f32x4 acc[4][4] = {};
    for (int k0 = 0; k0 < KB; k0 += 32) {
        int ka = (k0 < KA) ? k0 : k0 - KA;
        __syncthreads();
#pragma unroll
        for (int r = 0; r < 2; ++r) {
            async_copy16(&Al[(size_t)(wv * 16 + r * 64) * 32], a1p[r] + ka);
            async_copy16(&Bl[(size_t)(wv * 16 + r * 64) * 32], b1p[r] + k0);
        }
        __syncthreads();

        short8 aF[4], bF[4];
#pragma unroll
        for (int i = 0; i < 4; ++i) {
            aF[i] = *(const short8*)&Al[(size_t)(wm * 64 + i * 16 + l15) * 32 + swz];
            bF[i] = *(const short8*)&Bl[(size_t)(wn * 64 + i * 16 + l15) * 32 + swz];
        }
#pragma unroll
        for (int i = 0; i < 4; ++i)
#pragma unroll
            for (int j = 0; j < 4; ++j)
                acc[i][j] = __builtin_amdgcn_mfma_f32_16x16x32_bf16(aF[i], bF[j], acc[i][j], 0, 0, 0);
    }

#pragma unroll
    for (int i = 0; i < 4; ++i) {
        int mbase = m0 + wm * 64 + i * 16 + quad * 4;
#pragma unroll
        for (int j = 0; j < 4; ++j) {
            int n = n0 + wn * 64 + j * 16 + l15;
#pragma unroll
            for (int r = 0; r < 4; ++r) {
                int m = mbase + r;
                if (m < M) outf[(size_t)m * ldout + n] = acc[i][j][r];
            }
        }
    }
}

// ---------- combined per-level dispatch: blockIdx.y<4 -> f-path, else iou-path ----------
__global__ __launch_bounds__(256)
void combined_kernel(int nl,
                     const ushort_t* __restrict__ child_h, const float* __restrict__ c_prev,
                     const float* __restrict__ xf, const float* __restrict__ bias_f,
                     float* __restrict__ fc_out,
                     const ushort_t* __restrict__ x_lvl, const ushort_t* __restrict__ hsum,
                     const ushort_t* __restrict__ Wfh,
                     const ushort_t* __restrict__ Wioux, const ushort_t* __restrict__ Wiouh,
                     float* __restrict__ iou_f, ushort_t* __restrict__ iou_b) {
    __shared__ __align__(16) ushort_t Al[128 * 32];
    __shared__ __align__(16) ushort_t Bl[128 * 32];

    const int by = blockIdx.y;
    const bool fpath = by < 4;
    const int M = fpath ? 4 * nl : nl;
    const int m0 = blockIdx.x * 128;
    if (m0 >= M) return;
    const int n0 = (fpath ? by : by - 4) * 128;

    const ushort_t* A1 = fpath ? child_h : x_lvl;
    const ushort_t* A2 = fpath ? nullptr : hsum;
    const ushort_t* B1 = fpath ? Wfh : Wioux;
    const ushort_t* B2 = fpath ? nullptr : Wiouh;

    const int tid  = threadIdx.x;
    const int lane = tid & 63, wv = tid >> 6;
    const int l15  = lane & 15, quad = lane >> 4;
    const int wm   = wv >> 1, wn = wv & 1;

    const int srow = wv * 16 + (lane >> 2);
    const int kch  = ((lane & 3) ^ ((lane >> 3) & 3)) * 8;
    const int swz  = (quad ^ ((l15 >> 1) & 3)) * 8;

    const ushort_t* a1p[2]; const ushort_t* a2p[2];
    const ushort_t* b1p[2]; const ushort_t* b2p[2];
#pragma unroll
    for (int r = 0; r < 2; ++r) {
        int rl = m0 + srow + r * 64; if (rl > M - 1) rl = M - 1;
        a1p[r] = A1 + (size_t)rl * KA + kch;
        a2p[r] = A2 ? A2 + (size_t)rl * KA + kch : nullptr;
        int nb = n0 + srow + r * 64;
        b1p[r] = B1 + (size_t)nb * KB + kch;
        b2p[r] = B2 ? B2 + (size_t)nb * KB + kch : nullptr;
    }

    f32x4 acc[4][4] = {};
    const int nphase = A2 ? 2 : 1;
    for (int ph = 0; ph < nphase; ++ph) {
        for (int k0 = 0; k0 < KB; k0 += 32) {
            int ka = (k0 < KA) ? k0 : k0 - KA;
            __syncthreads();
#pragma unroll
            for (int r = 0; r < 2; ++r) {
                async_copy16(&Al[(size_t)(wv * 16 + r * 64) * 32], (ph ? a2p[r] : a1p[r]) + ka);
                async_copy16(&Bl[(size_t)(wv * 16 + r * 64) * 32], (ph ? b2p[r] : b1p[r]) + k0);
            }
            __syncthreads();

            short8 aF[4], bF[4];
#pragma unroll
            for (int i = 0; i < 4; ++i) {
                aF[i] = *(const short8*)&Al[(size_t)(wm * 64 + i * 16 + l15) * 32 + swz];
                bF[i] = *(const short8*)&Bl[(size_t)(wn * 64 + i * 16 + l15) * 32 + swz];
            }
#pragma unroll
            for (int i = 0; i < 4; ++i)
#pragma unroll
                for (int j = 0; j < 4; ++j)
                    acc[i][j] = __builtin_amdgcn_mfma_f32_16x16x32_bf16(aF[i], bF[j], acc[i][j], 0, 0, 0);
        }
    }

    if (fpath) {
#pragma unroll
        for (int i = 0; i < 4; ++i) {
            int mbase = m0 + wm * 64 + i * 16 + quad * 4;   // = 4*jg
            if (mbase < M) {
                int jg = mbase >> 2;
#pragma unroll
                for (int j = 0; j < 4; ++j) {
                    int n = n0 + wn * 64 + j * 16 + l15;
                    float add = xf[(size_t)jg * 512 + n] + bias_f[n];
                    float fc = 0.f;
#pragma unroll
                    for (int r = 0; r < 4; ++r) {
                        float f = sigmoidf(acc[i][j][r] + add);
                        fc += f * c_prev[(size_t)(mbase + r) * 512 + n];
                    }
                    fc_out[(size_t)jg * 512 + n] = fc;
                }
            }
        }
    } else {
#pragma unroll
        for (int i = 0; i < 4; ++i) {
            int mbase = m0 + wm * 64 + i * 16 + quad * 4;
#pragma unroll
            for (int j = 0; j < 4; ++j) {
                int n = n0 + wn * 64 + j * 16 + l15;
#pragma unroll
                for (int r = 0; r < 4; ++r) {
                    int m = mbase + r;
                    if (m < M) {
                        if (iou_b) iou_b[(size_t)m * 1536 + n] = f2bf(acc[i][j][r]);
                        else       iou_f[(size_t)m * 1536 + n] = acc[i][j][r];
                    }
                }
            }
        }
    }
}

// ---------- fused leaf: iou-GEMM + LSTM cell in-register ----------
__global__ __launch_bounds__(256)
void fused_leaf_kernel(int M,
                       const ushort_t* __restrict__ a1,
                       const ushort_t* __restrict__ b1,
                       const float* __restrict__ bias_iou,
                       float* __restrict__ c_out,
                       ushort_t* __restrict__ h_out) {
    __shared__ __align__(16) ushort_t Al[128 * 32];       // 8 KB
    __shared__ __align__(16) ushort_t Bl[3 * 64 * 32];    // 12 KB

    const int tid  = threadIdx.x;
    const int lane = tid & 63, wv = tid >> 6;
    const int l15  = lane & 15, quad = lane >> 4;
    const int m0   = blockIdx.x * 128;
    const int n0   = blockIdx.y * 64;

    const int srow = wv * 16 + (lane >> 2);
    const int kch  = ((lane & 3) ^ ((lane >> 3) & 3)) * 8;
    const int swz  = (quad ^ ((l15 >> 1) & 3)) * 8;

    const ushort_t* a1p[2]; const ushort_t* b1p[3];
#pragma unroll
    for (int r = 0; r < 2; ++r) {
        int rl = m0 + srow + r * 64; if (rl > M - 1) rl = M - 1;
        a1p[r] = a1 + (size_t)rl * KA + kch;
    }
#pragma unroll
    for (int g = 0; g < 3; ++g)
        b1p[g] = b1 + (size_t)(g * 512 + n0 + srow) * KB + kch;

    f32x4 acc[3][2][4] = {};
    for (int k0 = 0; k0 < KB; k0 += 32) {
        int ka = (k0 < KA) ? k0 : k0 - KA;
        __syncthreads();
#pragma unroll
        for (int r = 0; r < 2; ++r)
            async_copy16(&Al[(size_t)(wv * 16 + r * 64) * 32], a1p[r] + ka);
#pragma unroll
        for (int g = 0; g < 3; ++g)
            async_copy16(&Bl[(size_t)(g * 64 + wv * 16) * 32], b1p[g] + k0);
        __syncthreads();

        short8 aF[2];
#pragma unroll
        for (int i = 0; i < 2; ++i)
            aF[i] = *(const short8*)&Al[(size_t)(wv * 32 + i * 16 + l15) * 32 + swz];
#pragma unroll
        for (int g = 0; g < 3; ++g) {
            short8 bF[4];
#pragma unroll
            for (int j = 0; j < 4; ++j)
                bF[j] = *(const short8*)&Bl[(size_t)(g * 64 + j * 16 + l15) * 32 + swz];
#pragma unroll
            for (int i = 0; i < 2; ++i)
#pragma unroll
                for (int j = 0; j < 4; ++j)
                    acc[g][i][j] = __builtin_amdgcn_mfma_f32_16x16x32_bf16(aF[i], bF[j], acc[g][i][j], 0, 0, 0);
        }
    }

#pragma unroll
    for (int i = 0; i < 2; ++i) {
        int mbase = m0 + wv * 32 + i * 16 + quad * 4;
#pragma unroll
        for (int r = 0; r < 4; ++r) {
            int m = mbase + r;
            if (m < M) {
#pragma unroll
                for (int j = 0; j < 4; ++j) {
                    int n = n0 + j * 16 + l15;
                    float iv = sigmoidf(acc[0][i][j][r] + bias_iou[n]);
                    float ov = sigmoidf(acc[1][i][j][r] + bias_iou[512 + n]);
                    float uv = tanhf(  acc[2][i][j][r] + bias_iou[1024 + n]);
                    float c = iv * uv;
                    float h = ov * tanhf(c);
                    c_out[(size_t)m * 512 + n] = c;
                    ushort_t hi = f2bf(h), lo = f2bf(h - bf2f(hi));
                    h_out[(size_t)m * KA + n] = hi;
                    h_out[(size_t)m * KA + 512 + n] = lo;
                }
            }
        }
    }
}

// ---------- elementwise cell (L1/L2), 4 elems/thread; optional fp32-h side output ----------
template <bool IOU_BF>
__global__ void cell_kernel(const void* __restrict__ iou_v, const float* __restrict__ bias_iou,
                            const float* __restrict__ fc,
                            ushort_t* __restrict__ h_out, float* __restrict__ c_out,
                            int n4, float* __restrict__ outp, float* __restrict__ hf_out) {
    int t = blockIdx.x * blockDim.x + threadIdx.x;
    if (t >= n4) return;
    int j = t >> 7, m4 = (t & 127) * 4;
    float pi[4], po[4], pu[4];
    if constexpr (IOU_BF) {
        const ushort_t* row = (const ushort_t*)iou_v + (size_t)j * 1536;
        ushort4 a = *(const ushort4*)&row[m4];
        ushort4 b = *(const ushort4*)&row[512 + m4];
        ushort4 c = *(const ushort4*)&row[1024 + m4];
        pi[0]=bf2f(a.x); pi[1]=bf2f(a.y); pi[2]=bf2f(a.z); pi[3]=bf2f(a.w);
        po[0]=bf2f(b.x); po[1]=bf2f(b.y); po[2]=bf2f(b.z); po[3]=bf2f(b.w);
        pu[0]=bf2f(c.x); pu[1]=bf2f(c.y); pu[2]=bf2f(c.z); pu[3]=bf2f(c.w);
    } else {
        const float* row = (const float*)iou_v + (size_t)j * 1536;
        float4 a = *(const float4*)&row[m4];
        float4 b = *(const float4*)&row[512 + m4];
        float4 c = *(const float4*)&row[1024 + m4];
        pi[0]=a.x; pi[1]=a.y; pi[2]=a.z; pi[3]=a.w;
        po[0]=b.x; po[1]=b.y; po[2]=b.z; po[3]=b.w;
        pu[0]=c.x; pu[1]=c.y; pu[2]=c.z; pu[3]=c.w;
    }
    float4 bi = *(const float4*)&bias_iou[m4];
    float4 bo = *(const float4*)&bias_iou[512 + m4];
    float4 bu = *(const float4*)&bias_iou[1024 + m4];
    float4 fcv = *(const float4*)&fc[(size_t)j * 512 + m4];
    float bia[4] = {bi.x, bi.y, bi.z, bi.w};
    float boa[4] = {bo.x, bo.y, bo.z, bo.w};
    float bua[4] = {bu.x, bu.y, bu.z, bu.w};
    float fca[4] = {fcv.x, fcv.y, fcv.z, fcv.w};
    float cv[4], hv[4];
#pragma unroll
    for (int q = 0; q < 4; ++q) {
        float iv = sigmoidf(pi[q] + bia[q]);
        float ov = sigmoidf(po[q] + boa[q]);
        float uv = tanhf(  pu[q] + bua[q]);
        cv[q] = iv * uv + fca[q];
        hv[q] = ov * tanhf(cv[q]);
    }
    *(float4*)&c_out[(size_t)j * 512 + m4] = float4{cv[0], cv[1], cv[2], cv[3]};
    ushort4 hi, lo;
    hi.x = f2bf(hv[0]); lo.x = f2bf(hv[0] - bf2f(hi.x));
    hi.y = f2bf(hv[1]); lo.y = f2bf(hv[1] - bf2f(hi.y));
    hi.z = f2bf(hv[2]); lo.z = f2bf(hv[2] - bf2f(hi.z));
    hi.w = f2bf(hv[3]); lo.w = f2bf(hv[3] - bf2f(hi.w));
    ushort_t* hr = h_out + (size_t)j * KA;
    *(ushort4*)&hr[m4] = hi;
    *(ushort4*)&hr[512 + m4] = lo;
    if (hf_out) *(float4*)&hf_out[(size_t)j * 512 + m4] = float4{hv[0], hv[1], hv[2], hv[3]};
    if (outp) *(float4*)&outp[m4] = float4{hv[0], hv[1], hv[2], hv[3]};
}

// ================= persistent tail (levels 3..7, nl=256..1) =================
// R5/R7-PROVEN inter-block structure: 512 blocks, 9 grid barriers, hierarchical
// bucket barrier, relaxed poll + single acquire fence, global split-K partials.
// R8 change (intra-block only): child-h rows staged in LDS, read as broadcasts.

__device__ __forceinline__ void grid_barrier(unsigned* bar, unsigned base, unsigned step) {
    __syncthreads();
    if (threadIdx.x == 0) {
        __threadfence();   // release: make this block's stage writes visible
        const int bkt = (int)(blockIdx.x & (NXCD - 1));
        unsigned old = __hip_atomic_fetch_add(&bar[16 * bkt], 1u, __ATOMIC_ACQ_REL, __HIP_MEMORY_SCOPE_AGENT);
        if (((old + 1u) & (unsigned)(BPX - 1)) == 0u) {       // bucket complete for this step
            unsigned g = __hip_atomic_fetch_add(&bar[128], 1u, __ATOMIC_ACQ_REL, __HIP_MEMORY_SCOPE_AGENT);
            if (((g + 1u) & (unsigned)(NXCD - 1)) == 0u)      // all buckets complete
                __hip_atomic_fetch_add(&bar[144], 1u, __ATOMIC_ACQ_REL, __HIP_MEMORY_SCOPE_AGENT);
        }
        while ((unsigned)(__hip_atomic_load(&bar[144], __ATOMIC_RELAXED, __HIP_MEMORY_SCOPE_AGENT) - base) < step)
            __builtin_amdgcn_s_sleep(2);
        __threadfence();   // acquire ONCE: invalidate stale cache before reading stage data
    }
    __syncthreads();
}

// G-stage: unit (jg, s, n) per thread; n = 64*(blockIdx&7) + lane (XCD-local
// weight cols). For all levels S∈{4,16,64} the block's 4 consecutive subs share
// ONE jg -> block stages its 16 contiguous child-h rows (32KB LDS, coalesced),
// inner loop reads h as same-address LDS broadcasts (4x ds_read_b128 / 4k).
// K-split is by CONTIGUOUS chunk per s (any disjoint k-partition is valid; the
// cell just sums all s). iou-h = hsum@Wh ; f[r] = h_r@Wf -> fp32 partials.
template <int S, int NL>
__device__ void tail_gemm(int ioff, int ioffp,
                          const float* __restrict__ hf,
                          const float* __restrict__ Wh, const float* __restrict__ Wf,
                          float* __restrict__ iou_part, float* __restrict__ f_part,
                          float (*hst)[512]) {
    constexpr int JG = (NL + 3) >> 2;
    constexpr int KC = 512 / S;                    // contiguous k-chunk per unit
    const int base4 = (int)(blockIdx.x >> 3) * 4;
    if (base4 >= JG * S) return;                   // idle block (block-uniform)
    const int tid = (int)threadIdx.x;

    // stage 16 child-h rows for this block's jg (shared by all 4 waves)
    const int jg = base4 / S;                      // scalar (blockIdx-derived)
    {
        const int r  = tid >> 4;                   // 16 rows x 16 threads
        const int c0 = (tid & 15) * 4;
        const float* src = hf + (size_t)(ioffp - 4096 + 16 * jg + r) * 512;
#pragma unroll
        for (int i = 0; i < 8; ++i)
            *(float4*)&hst[r][c0 + i * 64] = *(const float4*)&src[c0 + i * 64];
    }
    __syncthreads();

    const int n = ((int)(blockIdx.x & 7) << 6) | (tid & 63);
    const int s = __builtin_amdgcn_readfirstlane(base4 % S + (tid >> 6));
    const int jbase = jg << 2;
    const int kbase = s * KC;

    float aI[4][3] = {}; float aF[4][4] = {};
    for (int kk = 0; kk < KC; kk += 4) {
        const int k = kbase + kk;
        float w0[4], w1[4], w2[4], wfv[4];
#pragma unroll
        for (int q = 0; q < 4; ++q) {
            const size_t kr = (size_t)(k + q) * 1536;
            w0[q] = Wh[kr + n]; w1[q] = Wh[kr + 512 + n]; w2[q] = Wh[kr + 1024 + n];
            wfv[q] = Wf[(size_t)(k + q) * 512 + n];
        }
#pragma unroll
        for (int p = 0; p < 4; ++p) {
            f32x4 h0v = *(const f32x4*)&hst[4 * p + 0][k];
            f32x4 h1v = *(const f32x4*)&hst[4 * p + 1][k];
            f32x4 h2v = *(const f32x4*)&hst[4 * p + 2][k];
            f32x4 h3v = *(const f32x4*)&hst[4 * p + 3][k];
#pragma unroll
            for (int q = 0; q < 4; ++q) {
                float h0 = h0v[q], h1 = h1v[q], h2 = h2v[q], h3 = h3v[q];
                float hs = (h0 + h1) + (h2 + h3);
                aI[p][0] += hs * w0[q]; aI[p][1] += hs * w1[q]; aI[p][2] += hs * w2[q];
                aF[p][0] += h0 * wfv[q]; aF[p][1] += h1 * wfv[q];
                aF[p][2] += h2 * wfv[q]; aF[p][3] += h3 * wfv[q];
            }
        }
    }
#pragma unroll
    for (int p = 0; p < 4; ++p) {
        int j = jbase + p;
        if (j < NL) {
#pragma unroll
            for (int g = 0; g < 3; ++g)
                iou_part[(((size_t)s * NL + j) * 3 + g) * 512 + n] = aI[p][g];
#pragma unroll
            for (int r = 0; r < 4; ++r)
                f_part[((size_t)s * 4 * NL + 4 * j + r) * 512 + n] = aF[p][r];
        }
    }
}

// C-stage: unit (j, n) per thread; sums S partials, adds precomputed xiou
// (x@Wioux) + biases, applies gates, writes c/h (fp32). NL==1 -> root output.
template <int S, int NL>
__device__ void tail_cell(int ioff, int ioffp,
                          const float* __restrict__ xiou,
                          float* __restrict__ hf, float* __restrict__ c_int,
                          const float* __restrict__ xf,
                          const float* __restrict__ bias_iou, const float* __restrict__ bias_f,
                          const float* __restrict__ iou_part, const float* __restrict__ f_part,
                          float* __restrict__ out) {
    int sub = (int)(blockIdx.x >> 3) * 4 + (int)(threadIdx.x >> 6);
    if (sub >= NL) return;
    const int n = ((int)(blockIdx.x & 7) << 6) | ((int)threadIdx.x & 63);
    const int j = __builtin_amdgcn_readfirstlane(sub);
    const size_t xr = (size_t)(ioff - 5120 + j) * 1536;
    float g0 = xiou[xr + n]        + bias_iou[n];
    float g1 = xiou[xr + 512 + n]  + bias_iou[512 + n];
    float g2 = xiou[xr + 1024 + n] + bias_iou[1024 + n];
    float f0 = 0.f, f1 = 0.f, f2 = 0.f, f3 = 0.f;
#pragma unroll 4
    for (int s = 0; s < S; ++s) {
        const float* ip = iou_part + (((size_t)s * NL + j) * 3) * 512 + n;
        g0 += ip[0]; g1 += ip[512]; g2 += ip[1024];
        const float* fp = f_part + ((size_t)s * 4 * NL + 4 * j) * 512 + n;
        f0 += fp[0]; f1 += fp[512]; f2 += fp[1024]; f3 += fp[1536];
    }
    float iv = sigmoidf(g0), ov = sigmoidf(g1), uv = tanhf(g2);
    float add = xf[(size_t)(ioff + j) * 512 + n] + bias_f[n];
    float fc = sigmoidf(f0 + add) * c_int[(size_t)(ioffp + 4 * j + 0) * 512 + n]
             + sigmoidf(f1 + add) * c_int[(size_t)(ioffp + 4 * j + 1) * 512 + n]
             + sigmoidf(f2 + add) * c_int[(size_t)(ioffp + 4 * j + 2) * 512 + n]
             + sigmoidf(f3 + add) * c_int[(size_t)(ioffp + 4 * j + 3) * 512 + n];
    float c = iv * uv + fc;
    float h = ov * tanhf(c);
    c_int[(size_t)(ioff + j) * 512 + n] = c;
    hf[(size_t)(ioff - 4096 + j) * 512 + n] = h;
    if (NL == 1) out[n] = h;   // root
}

__global__ __launch_bounds__(256, 4)
void tail_kernel(const float* __restrict__ xiou, float* __restrict__ hf,
                 float* __restrict__ c_int, const float* __restrict__ xf,
                 const float* __restrict__ Wh, const float* __restrict__ Wf,
                 const float* __restrict__ bias_iou, const float* __restrict__ bias_f,
                 float* __restrict__ iou_part, float* __restrict__ f_part,
                 unsigned* __restrict__ bar, float* __restrict__ out) {
    __shared__ float hst[16][512];   // 32 KB child-h staging
    __shared__ unsigned s_base;
    if (threadIdx.x == 0)
        s_base = __hip_atomic_load(&bar[144], __ATOMIC_RELAXED, __HIP_MEMORY_SCOPE_AGENT);
    __syncthreads();
    const unsigned base = s_base;
    unsigned step = 0;

    // L3: nl=256
    tail_gemm<4, 256>(5120, 4096, hf, Wh, Wf, iou_part, f_part, hst);
    grid_barrier(bar, base, ++step);
    tail_cell<4, 256>(5120, 4096, xiou, hf, c_int, xf, bias_iou, bias_f, iou_part, f_part, out);
    grid_barrier(bar, base, ++step);
    // L4: nl=64
    tail_gemm<16, 64>(5376, 5120, hf, Wh, Wf, iou_part, f_part, hst);
    grid_barrier(bar, base, ++step);
    tail_cell<16, 64>(5376, 5120, xiou, hf, c_int, xf, bias_iou, bias_f, iou_part, f_part, out);
    grid_barrier(bar, base, ++step);
    // L5: nl=16
    tail_gemm<64, 16>(5440, 5376, hf, Wh, Wf, iou_part, f_part, hst);
    grid_barrier(bar, base, ++step);
    tail_cell<64, 16>(5440, 5376, xiou, hf, c_int, xf, bias_iou, bias_f, iou_part, f_part, out);
    grid_barrier(bar, base, ++step);
    // L6: nl=4
    tail_gemm<64, 4>(5456, 5440, hf, Wh, Wf, iou_part, f_part, hst);
    grid_barrier(bar, base, ++step);
    tail_cell<64, 4>(5456, 5440, xiou, hf, c_int, xf, bias_iou, bias_f, iou_part, f_part, out);
    grid_barrier(bar, base, ++step);
    // L7 (root): nl=1
    tail_gemm<64, 1>(5460, 5456, hf, Wh, Wf, iou_part, f_part, hst);
    grid_barrier(bar, base, ++step);
    tail_cell<64, 1>(5460, 5456, xiou, hf, c_int, xf, bias_iou, bias_f, iou_part, f_part, out);
}

// ---------- host ----------
extern "C" void kernel_launch(void* const* d_in, const int* in_sizes, int n_in,
                              void* d_out, int out_size, void* d_ws, size_t ws_size,
                              hipStream_t stream) {
    const float* x       = (const float*)d_in[0];
    // d_in[1] = children: fixed complete 4-ary tree, contiguous levels — not needed
    const float* W_ioux  = (const float*)d_in[2];
    const float* b_ioux  = (const float*)d_in[3];
    const float* W_iouh  = (const float*)d_in[4];
    const float* b_iouh  = (const float*)d_in[5];
    const float* W_fx    = (const float*)d_in[6];
    const float* b_fx    = (const float*)d_in[7];
    const float* W_fh    = (const float*)d_in[8];
    const float* b_fh    = (const float*)d_in[9];
    float* out = (float*)d_out;
    char* ws = (char*)d_ws;

    ushort_t* WTioux = (ushort_t*)(ws + OFF_WTIOUX);
    ushort_t* WTiouh = (ushort_t*)(ws + OFF_WTIOUH);
    ushort_t* WTfx   = (ushort_t*)(ws + OFF_WTFX);
    ushort_t* WTfh   = (ushort_t*)(ws + OFF_WTFH);
    float*    bias_iou = (float*)(ws + OFF_BIASIOU);
    float*    bias_f   = (float*)(ws + OFF_BIASF);
    ushort_t* x_hl   = (ushort_t*)(ws + OFF_XHL);
    ushort_t* h_int  = x_hl;                               // rows 0..5460 (dead leaf x)
    ushort_t* iou_b  = x_hl + (size_t)5464 * KA;           // rows 5464.. (dead leaf x)
    float*    iou_f  = (float*)iou_b;
    ushort_t* h_leaf = (ushort_t*)(ws + OFF_HLEAF);
    float*    c_int  = (float*)(ws + OFF_HLEAF);           // alias; live after h_leaf dead
    float*    xf32   = (float*)(ws + OFF_XF);
    ushort_t* hsum_hl= (ushort_t*)(ws + OFF_HSUM);
    float*    c_leaf = (float*)(ws + OFF_CLEAF);
    float*    fc_buf = (float*)(ws + OFF_FC);
    // tail-only views over dead regions:
    float*    hf32     = (float*)(ws + OFF_CLEAF);         // fp32 h rows (ioff-4096); c_leaf dead after combined(L1)
    float*    xiou     = fc_buf;                           // 341x1536 fp32 (2.1MB); fc dead after cell(L2)
    float*    iou_part = iou_f;                            // 6.3MB, iou scratch dead after cell(L2)
    float*    f_part   = iou_f + 1572864;                  // 8.4MB, inside dead region (14.7 < 22.4MB)
    unsigned* barp     = (unsigned*)(x_hl + (size_t)21845 * KA);  // never-written pad rows

    wsplit_kernel<<<dim3(16, 48), dim3(32, 8), 0, stream>>>(W_ioux, WTioux, 1536);
    wsplit_kernel<<<dim3(16, 48), dim3(32, 8), 0, stream>>>(W_iouh, WTiouh, 1536);
    wsplit_kernel<<<dim3(16, 16), dim3(32, 8), 0, stream>>>(W_fx,   WTfx,   512);
    wsplit_kernel<<<dim3(16, 16), dim3(32, 8), 0, stream>>>(W_fh,   WTfh,   512);
    bias_kernel<<<6, 256, 0, stream>>>(b_ioux, b_iouh, b_fx, b_fh, bias_iou, bias_f, barp);

    // all-node x expansion
    xexp_kernel<<<(NNODE * 128 + 255) / 256, 256, 0, stream>>>(x, x_hl, NNODE * 128);

    // x_f for internal nodes (once): M=5461, N=512
    gemm_kernel<<<dim3(43, 4), 256, 0, stream>>>(
        NINT, x_hl + (size_t)NLEAF * KA, WTfx, xf32, 512);

    // ---- leaf level: fused iou-GEMM + cell ----
    fused_leaf_kernel<<<dim3(128, 8), 256, 0, stream>>>(
        NLEAF, x_hl, WTioux, bias_iou, c_leaf, h_leaf);

    // ---- level 1 (nl=4096): hsum -> combined(f || iou bf16) -> cell ----
    {
        const int nl = 4096, n4 = nl * 128, M4 = 4 * nl;
        hsum_kernel<<<(n4 + 255) / 256, 256, 0, stream>>>(h_leaf, hsum_hl, n4);
        combined_kernel<<<dim3((M4 + 127) / 128, 16), 256, 0, stream>>>(
            nl, h_leaf, c_leaf, xf32, bias_f, fc_buf,
            x_hl + (size_t)16384 * KA, hsum_hl, WTfh, WTioux, WTiouh,
            nullptr, iou_b);
        cell_kernel<true><<<(n4 + 255) / 256, 256, 0, stream>>>(
            iou_b, bias_iou, fc_buf, h_int, c_int, n4, nullptr, nullptr);
    }
    // ---- level 2 (nl=1024): hsum -> combined(f || iou fp32) -> cell (+fp32 h for tail) ----
    {
        const int nl = 1024, n4 = nl * 128, M4 = 4 * nl, ioff = 4096;
        hsum_kernel<<<(n4 + 255) / 256, 256, 0, stream>>>(h_int, hsum_hl, n4);
        combined_kernel<<<dim3((M4 + 127) / 128, 16), 256, 0, stream>>>(
            nl, h_int, c_int, xf32 + (size_t)ioff * 512, bias_f, fc_buf,
            x_hl + (size_t)20480 * KA, hsum_hl, WTfh, WTioux, WTiouh,
            iou_f, nullptr);
        cell_kernel<false><<<(n4 + 255) / 256, 256, 0, stream>>>(
            iou_f, bias_iou, fc_buf, h_int + (size_t)ioff * KA, c_int + (size_t)ioff * 512,
            n4, nullptr, hf32);
    }
    // ---- x_iou for tail nodes 5120..5460 (M=341, N=1536) -> xiou (fc region) ----
    gemm_kernel<<<dim3(3, 12), 256, 0, stream>>>(
        341, x_hl + (size_t)(NLEAF + 5120) * KA, WTioux, xiou, 1536);

    // ---- levels 3..7 (nl=256..1): one persistent fp32-VALU kernel, 9 grid barriers ----
    tail_kernel<<<TAILB, 256, 0, stream>>>(
        xiou, hf32, c_int, xf32, W_iouh, W_fh, bias_iou, bias_f,
        iou_part, f_part, barp, out);

    (void)d_in; (void)in_sizes; (void)n_in; (void)out_size; (void)ws_size;
}